// Round 2
// baseline (1294.926 us; speedup 1.0000x reference)
//
#include <hip/hip_runtime.h>

#define HIDDEN 2048
#define HEADS 16
#define HDIM 128
#define BQ 8
#define QLEN 1024
#define KVLEN 4096
#define MROWS (BQ * QLEN)  // 8192

typedef __bf16 bf16x8 __attribute__((ext_vector_type(8)));
typedef float f32x4 __attribute__((ext_vector_type(4)));
typedef unsigned short u16;
typedef u16 u16x8 __attribute__((ext_vector_type(8)));
typedef float f32x8v __attribute__((ext_vector_type(8)));

// fp32 -> bf16 bits, round-to-nearest-even
__device__ __forceinline__ u16 f2bf(float f) {
  union { float f; unsigned u; } v; v.f = f;
  unsigned r = (v.u + 0x7FFFu + ((v.u >> 16) & 1u)) >> 16;
  return (u16)r;
}

// async global->LDS, 16B per lane; LDS dest = wave-uniform base + lane*16
__device__ __forceinline__ void async_ld16(const void* g, void* l) {
  __builtin_amdgcn_global_load_lds(
      (const __attribute__((address_space(1))) void*)g,
      (__attribute__((address_space(3))) void*)l, 16, 0, 0);
}

// fp32 -> bf16 narrowing copy
__global__ void convert_bf16(const float* __restrict__ src, u16* __restrict__ dst,
                             long n) {
  long base = ((long)blockIdx.x * blockDim.x + threadIdx.x) * 8;
  long stride = (long)gridDim.x * blockDim.x * 8;
  for (long i = base; i < n; i += stride) {
    f32x8v s = *(const f32x8v*)(src + i);
    u16x8 o;
#pragma unroll
    for (int j = 0; j < 8; j++) o[j] = f2bf(s[j]);
    *(u16x8*)(dst + i) = o;
  }
}

// V fp32 [KVLEN][HIDDEN] -> Vt bf16 [HEADS*HDIM][KVLEN] (per-head transpose),
// fused with the bf16 conversion. Done ONCE: V is shared across batch and
// q-tiles, so this kills the per-block per-tile scalar transpose in attn.
__global__ __launch_bounds__(256) void transpose_v(const float* __restrict__ V,
                                                   u16* __restrict__ Vt) {
  __shared__ u16 T[128][129];
  const int kv0 = blockIdx.x * 128;
  const int h = blockIdx.y;
  const int tid = threadIdx.x;
#pragma unroll
  for (int p = 0; p < 8; p++) {
    int idx = p * 2048 + tid * 8;
    int r = idx >> 7, c = idx & 127;  // kv-row, d-col
    f32x8v s = *(const f32x8v*)(V + (size_t)(kv0 + r) * HIDDEN + h * HDIM + c);
#pragma unroll
    for (int j = 0; j < 8; j++) T[r][c + j] = f2bf(s[j]);
  }
  __syncthreads();
#pragma unroll
  for (int p = 0; p < 8; p++) {
    int idx = p * 2048 + tid * 8;
    int d = idx >> 7, kv = idx & 127;
    u16x8 o;
#pragma unroll
    for (int j = 0; j < 8; j++) o[j] = T[kv + j][d];
    *(u16x8*)(Vt + ((size_t)h * HDIM + d) * KVLEN + kv0 + kv) = o;
  }
}

// C[M][N] = A[M][K] @ Bt[N][K]^T  (bf16 in, fp32 accum; out bf16 or fp32 per flag)
// 128x128 tile, 4 waves (2x2), each wave 64x64 = 4x4 frags of 16x16x32 MFMA.
// XCD-aware swizzle: each XCD gets contiguous row-panels -> A-panel L2 reuse.
__global__ __launch_bounds__(256) void gemm_bt(
    const u16* __restrict__ A, const u16* __restrict__ Bt, void* __restrict__ C,
    int M, int N, int K, int outf) {
  __shared__ __align__(16) u16 Asm[4 * 128 * 8];
  __shared__ __align__(16) u16 Bsm[4 * 128 * 8];
  const int tid = threadIdx.x;
  const int wid = tid >> 6, lane = tid & 63;
  const int quad = lane >> 4, l15 = lane & 15;
  const int wm = wid >> 1, wn = wid & 1;
  // nwg = 1024 for both calls (16 x 64), divisible by 8 -> simple swizzle valid
  const int lin = blockIdx.y * gridDim.x + blockIdx.x;
  const int cpx = (gridDim.x * gridDim.y) >> 3;
  const int swz = (lin & 7) * cpx + (lin >> 3);
  const int by = swz / gridDim.x;
  const int bx = swz - by * gridDim.x;
  const int row0 = by * 128;
  const int col0 = bx * 128;

  f32x4 acc[4][4];
#pragma unroll
  for (int i = 0; i < 4; i++)
#pragma unroll
    for (int j = 0; j < 4; j++) acc[i][j] = (f32x4){0.f, 0.f, 0.f, 0.f};

  for (int k0 = 0; k0 < K; k0 += 32) {
    __syncthreads();  // prev iter's ds_reads done before overwrite
#pragma unroll
    for (int i = 0; i < 4; i++) {
      int seg = wid + 4 * i;          // 0..15
      int isB = seg >> 3;
      int s = seg & 7;
      int q = s >> 1, hv = s & 1;     // k-quad, m-half
      const u16* gsrc = isB ? Bt : A;
      int grow = (isB ? col0 : row0) + hv * 64 + lane;
      const u16* g = gsrc + (size_t)grow * K + (k0 + q * 8);
      u16* l = (isB ? Bsm : Asm) + (q * 128 + hv * 64) * 8;  // wave-uniform
      async_ld16(g, l);
    }
    __syncthreads();  // drains vmcnt -> LDS ready
    bf16x8 af[4], bfr[4];
#pragma unroll
    for (int mt = 0; mt < 4; mt++)
      af[mt] = *(const bf16x8*)(Asm + (quad * 128 + wm * 64 + mt * 16 + l15) * 8);
#pragma unroll
    for (int nt = 0; nt < 4; nt++)
      bfr[nt] = *(const bf16x8*)(Bsm + (quad * 128 + wn * 64 + nt * 16 + l15) * 8);
#pragma unroll
    for (int mt = 0; mt < 4; mt++)
#pragma unroll
      for (int nt = 0; nt < 4; nt++)
        acc[mt][nt] = __builtin_amdgcn_mfma_f32_16x16x32_bf16(af[mt], bfr[nt], acc[mt][nt], 0, 0, 0);
  }

#pragma unroll
  for (int mt = 0; mt < 4; mt++)
#pragma unroll
    for (int r = 0; r < 4; r++) {
      int row = row0 + wm * 64 + mt * 16 + quad * 4 + r;
#pragma unroll
      for (int nt = 0; nt < 4; nt++) {
        int col = col0 + wn * 64 + nt * 16 + l15;
        if (outf) {
          ((float*)C)[(size_t)row * N + col] = acc[mt][nt][r];
        } else {
          ((u16*)C)[(size_t)row * N + col] = f2bf(acc[mt][nt][r]);
        }
      }
    }
}

// Flash attention. 256 thr = 4 waves, wave owns 32 q rows; KVBLK=64.
// LDS: Kb 16K + Vb 16K + Pb 18K = 50KB -> 3 blocks/CU (was 2).
// V comes pre-transposed (Vt[h*128+d][kv]) -> staged via async 16B loads,
// issued AFTER the K-ready barrier so V latency hides under QK^T+softmax.
__global__ __launch_bounds__(256, 3) void attn(
    const u16* __restrict__ Q,   // [MROWS][HIDDEN] bf16
    const u16* __restrict__ Kv,  // [KVLEN][HIDDEN] bf16
    const u16* __restrict__ Vt,  // [HEADS*HDIM][KVLEN] bf16 (per-head V^T)
    u16* __restrict__ O) {       // [MROWS][HIDDEN] bf16
  __shared__ __align__(16) u16 Kb[16 * 512];  // [ch=d/8][kv 64][8d]
  __shared__ __align__(16) u16 Vb[8 * 1024];  // [ch=kv/8][d 128][8kv]
  __shared__ __align__(16) u16 Pb[128 * 72];  // [q][64+8 pad]
  const int tid = threadIdx.x;
  const int wid = tid >> 6, lane = tid & 63;
  const int quad = lane >> 4, l15 = lane & 15;
  // XCD swizzle: chunk of 128 consecutive ids = 2 heads -> K+V 4MB = one L2
  const int lin = blockIdx.x + (blockIdx.y << 3) + (blockIdx.z << 7);
  const int swz = ((lin & 7) << 7) + (lin >> 3);
  const int h = swz >> 6, b = (swz >> 3) & 7, qt = swz & 7;
  const int qrow0 = b * QLEN + qt * 128;
  const int hcol = h * HDIM;
  const float cexp = 0.08838834764831845f * 1.4426950408889634f;  // SCALE*log2(e)

  bf16x8 qf[2][4];
#pragma unroll
  for (int mt = 0; mt < 2; mt++)
#pragma unroll
    for (int ks = 0; ks < 4; ks++) {
      int row = qrow0 + wid * 32 + mt * 16 + l15;
      qf[mt][ks] = *(const bf16x8*)(Q + (size_t)row * HIDDEN + hcol + ks * 32 + quad * 8);
    }

  f32x4 o[2][8];
#pragma unroll
  for (int mt = 0; mt < 2; mt++)
#pragma unroll
    for (int dt = 0; dt < 8; dt++) o[mt][dt] = (f32x4){0.f, 0.f, 0.f, 0.f};
  float mrun[2][4], lrun[2][4];
#pragma unroll
  for (int mt = 0; mt < 2; mt++)
#pragma unroll
    for (int r = 0; r < 4; r++) { mrun[mt][r] = -INFINITY; lrun[mt][r] = 0.f; }

  for (int kv0 = 0; kv0 < KVLEN; kv0 += 64) {
    __syncthreads();  // (a) prev PV reads of Vb/Pb done, prev Kb reads long done
#pragma unroll
    for (int i = 0; i < 4; i++) {
      int s = wid + (i << 2);  // 0..15 = d-octet
      const u16* g = Kv + (size_t)(kv0 + lane) * HIDDEN + hcol + s * 8;
      async_ld16(g, Kb + s * 512);
    }
    __syncthreads();  // (b) K ready
    // issue V stage now; drains at (c) -> latency hidden under QK^T+softmax
#pragma unroll
    for (int i = 0; i < 4; i++) {
      int s = wid + (i << 2);              // 0..15
      int d = ((s & 1) << 6) + lane;       // d-half + lane
      const u16* g = Vt + ((size_t)hcol + d) * KVLEN + kv0 + ((s >> 1) << 3);
      async_ld16(g, Vb + s * 512);
    }

    f32x4 sc[2][4];
#pragma unroll
    for (int mt = 0; mt < 2; mt++)
#pragma unroll
      for (int nt = 0; nt < 4; nt++) sc[mt][nt] = (f32x4){0.f, 0.f, 0.f, 0.f};
#pragma unroll
    for (int ks = 0; ks < 4; ks++) {
      bf16x8 kf[4];
#pragma unroll
      for (int nt = 0; nt < 4; nt++)
        kf[nt] = *(const bf16x8*)(Kb + ((ks * 4 + quad) << 9) + ((nt * 16 + l15) << 3));
#pragma unroll
      for (int mt = 0; mt < 2; mt++)
#pragma unroll
        for (int nt = 0; nt < 4; nt++)
          sc[mt][nt] = __builtin_amdgcn_mfma_f32_16x16x32_bf16(qf[mt][ks], kf[nt], sc[mt][nt], 0, 0, 0);
    }

#pragma unroll
    for (int mt = 0; mt < 2; mt++) {
#pragma unroll
      for (int r = 0; r < 4; r++) {
        float mx = sc[mt][0][r];
#pragma unroll
        for (int nt = 1; nt < 4; nt++) mx = fmaxf(mx, sc[mt][nt][r]);
#pragma unroll
        for (int off = 1; off < 16; off <<= 1) mx = fmaxf(mx, __shfl_xor(mx, off, 64));
        float mn = fmaxf(mrun[mt][r], mx);
        float al = __builtin_amdgcn_exp2f((mrun[mt][r] - mn) * cexp);
        mrun[mt][r] = mn;
        float mc = mn * cexp;
        float ps = 0.f;
#pragma unroll
        for (int nt = 0; nt < 4; nt++) {
          float p = __builtin_amdgcn_exp2f(sc[mt][nt][r] * cexp - mc);
          sc[mt][nt][r] = p;
          ps += p;
        }
#pragma unroll
        for (int off = 1; off < 16; off <<= 1) ps += __shfl_xor(ps, off, 64);
        lrun[mt][r] = lrun[mt][r] * al + ps;
#pragma unroll
        for (int dt = 0; dt < 8; dt++) o[mt][dt][r] *= al;
      }
    }

#pragma unroll
    for (int mt = 0; mt < 2; mt++)
#pragma unroll
      for (int nt = 0; nt < 4; nt++)
#pragma unroll
        for (int r = 0; r < 4; r++) {
          int prow = wid * 32 + mt * 16 + quad * 4 + r;
          Pb[prow * 72 + nt * 16 + l15] = f2bf(sc[mt][nt][r]);
        }
    __syncthreads();  // (c) P writes visible + V loads drained

#pragma unroll
    for (int ks = 0; ks < 2; ks++) {
      bf16x8 pf[2], vf[8];
#pragma unroll
      for (int mt = 0; mt < 2; mt++)
        pf[mt] = *(const bf16x8*)(Pb + (wid * 32 + mt * 16 + l15) * 72 + ks * 32 + quad * 8);
#pragma unroll
      for (int dt = 0; dt < 8; dt++)
        vf[dt] = *(const bf16x8*)(Vb + ((ks * 4 + quad) << 10) + ((dt * 16 + l15) << 3));
#pragma unroll
      for (int mt = 0; mt < 2; mt++)
#pragma unroll
        for (int dt = 0; dt < 8; dt++)
          o[mt][dt] = __builtin_amdgcn_mfma_f32_16x16x32_bf16(pf[mt], vf[dt], o[mt][dt], 0, 0, 0);
    }
  }

#pragma unroll
  for (int mt = 0; mt < 2; mt++)
#pragma unroll
    for (int r = 0; r < 4; r++) {
      float inv = 1.0f / lrun[mt][r];
      int row = qrow0 + wid * 32 + mt * 16 + quad * 4 + r;
#pragma unroll
      for (int dt = 0; dt < 8; dt++) {
        int col = hcol + dt * 16 + l15;
        O[(size_t)row * HIDDEN + col] = f2bf(o[mt][dt][r] * inv);
      }
    }
}

extern "C" void kernel_launch(void* const* d_in, const int* in_sizes, int n_in,
                              void* d_out, int out_size, void* d_ws, size_t ws_size,
                              hipStream_t stream) {
  const float* query = (const float*)d_in[0];
  const float* kv_k  = (const float*)d_in[1];
  const float* kv_v  = (const float*)d_in[2];
  const float* Wq    = (const float*)d_in[3];
  const float* Wo    = (const float*)d_in[4];
  float* out = (float*)d_out;

  const long NQ = (long)MROWS * HIDDEN;   // 16.78M
  const long NK = (long)KVLEN * HIDDEN;   // 8.39M
  const long NW = (long)HIDDEN * HIDDEN;  // 4.19M

  dim3 blk(256);

  // ws (u16): [convQ NQ][convK NK][Vt NK][convWq NW][convWo NW][Qws NQ]; Ows aliases convQ.
  u16* convQ  = (u16*)d_ws;
  u16* convK  = convQ + NQ;
  u16* Vtb    = convK + NK;
  u16* convWq = Vtb + NK;
  u16* convWo = convWq + NW;
  u16* Qws    = convWo + NW;
  u16* Ows    = convQ;  // convQ dead after gemm1

  convert_bf16<<<dim3((NQ / 8 + 255) / 256), blk, 0, stream>>>(query, convQ,  NQ);
  convert_bf16<<<dim3((NK / 8 + 255) / 256), blk, 0, stream>>>(kv_k,  convK,  NK);
  transpose_v<<<dim3(KVLEN / 128, HEADS), blk, 0, stream>>>(kv_v, Vtb);
  convert_bf16<<<dim3((NW / 8 + 255) / 256), blk, 0, stream>>>(Wq,    convWq, NW);
  convert_bf16<<<dim3((NW / 8 + 255) / 256), blk, 0, stream>>>(Wo,    convWo, NW);

  gemm_bt<<<dim3(HIDDEN / 128, MROWS / 128), blk, 0, stream>>>(convQ, convWq, Qws, MROWS, HIDDEN, HIDDEN, 0);
  attn<<<dim3(QLEN / 128, HEADS, BQ), blk, 0, stream>>>(Qws, convK, Vtb, Ows);
  gemm_bt<<<dim3(HIDDEN / 128, MROWS / 128), blk, 0, stream>>>(Ows, convWo, out, MROWS, HIDDEN, HIDDEN, 1);
}

// Round 3
// 1047.839 us; speedup vs baseline: 1.2358x; 1.2358x over previous
//
#include <hip/hip_runtime.h>

#define HIDDEN 2048
#define HEADS 16
#define HDIM 128
#define BQ 8
#define QLEN 1024
#define KVLEN 4096
#define MROWS (BQ * QLEN)  // 8192

typedef __bf16 bf16x8 __attribute__((ext_vector_type(8)));
typedef float f32x4 __attribute__((ext_vector_type(4)));
typedef unsigned short u16;
typedef u16 u16x8 __attribute__((ext_vector_type(8)));
typedef float f32x8v __attribute__((ext_vector_type(8)));

// fp32 -> bf16 bits, round-to-nearest-even
__device__ __forceinline__ u16 f2bf(float f) {
  union { float f; unsigned u; } v; v.f = f;
  unsigned r = (v.u + 0x7FFFu + ((v.u >> 16) & 1u)) >> 16;
  return (u16)r;
}

// async global->LDS, 16B per lane; LDS dest = wave-uniform base + lane*16
__device__ __forceinline__ void async_ld16(const void* g, void* l) {
  __builtin_amdgcn_global_load_lds(
      (const __attribute__((address_space(1))) void*)g,
      (__attribute__((address_space(3))) void*)l, 16, 0, 0);
}

// fp32 -> bf16 narrowing copy
__global__ void convert_bf16(const float* __restrict__ src, u16* __restrict__ dst,
                             long n) {
  long base = ((long)blockIdx.x * blockDim.x + threadIdx.x) * 8;
  long stride = (long)gridDim.x * blockDim.x * 8;
  for (long i = base; i < n; i += stride) {
    f32x8v s = *(const f32x8v*)(src + i);
    u16x8 o;
#pragma unroll
    for (int j = 0; j < 8; j++) o[j] = f2bf(s[j]);
    *(u16x8*)(dst + i) = o;
  }
}

// V fp32 [KVLEN][HIDDEN] -> Vt bf16 [HEADS*HDIM][KVLEN] (per-head transpose),
// fused with bf16 conversion. Done ONCE: V is shared across batch and q-tiles.
__global__ __launch_bounds__(256) void transpose_v(const float* __restrict__ V,
                                                   u16* __restrict__ Vt) {
  __shared__ u16 T[128][129];
  const int kv0 = blockIdx.x * 128;
  const int h = blockIdx.y;
  const int tid = threadIdx.x;
#pragma unroll
  for (int p = 0; p < 8; p++) {
    int idx = p * 2048 + tid * 8;
    int r = idx >> 7, c = idx & 127;  // kv-row, d-col
    f32x8v s = *(const f32x8v*)(V + (size_t)(kv0 + r) * HIDDEN + h * HDIM + c);
#pragma unroll
    for (int j = 0; j < 8; j++) T[r][c + j] = f2bf(s[j]);
  }
  __syncthreads();
#pragma unroll
  for (int p = 0; p < 8; p++) {
    int idx = p * 2048 + tid * 8;
    int d = idx >> 7, kv = idx & 127;
    u16x8 o;
#pragma unroll
    for (int j = 0; j < 8; j++) o[j] = T[kv + j][d];
    *(u16x8*)(Vt + ((size_t)h * HDIM + d) * KVLEN + kv0 + kv) = o;
  }
}

// C[M][N] = A[M][K] @ Bt[N][K]^T  (bf16 in, fp32 accum; out bf16 or fp32)
// 128x128 tile, 4 waves (2x2), each wave 64x64 = 4x4 frags of 16x16x32 MFMA.
__global__ __launch_bounds__(256) void gemm_bt(
    const u16* __restrict__ A, const u16* __restrict__ Bt, void* __restrict__ C,
    int M, int N, int K, int outf) {
  __shared__ __align__(16) u16 Asm[4 * 128 * 8];
  __shared__ __align__(16) u16 Bsm[4 * 128 * 8];
  const int tid = threadIdx.x;
  const int wid = tid >> 6, lane = tid & 63;
  const int quad = lane >> 4, l15 = lane & 15;
  const int wm = wid >> 1, wn = wid & 1;
  // nwg = 1024 (16 x 64), divisible by 8 -> simple XCD swizzle is bijective
  const int lin = blockIdx.y * gridDim.x + blockIdx.x;
  const int cpx = (gridDim.x * gridDim.y) >> 3;
  const int swz = (lin & 7) * cpx + (lin >> 3);
  const int by = swz / gridDim.x;
  const int bx = swz - by * gridDim.x;
  const int row0 = by * 128;
  const int col0 = bx * 128;

  f32x4 acc[4][4];
#pragma unroll
  for (int i = 0; i < 4; i++)
#pragma unroll
    for (int j = 0; j < 4; j++) acc[i][j] = (f32x4){0.f, 0.f, 0.f, 0.f};

  for (int k0 = 0; k0 < K; k0 += 32) {
    __syncthreads();  // prev iter's ds_reads done before overwrite
#pragma unroll
    for (int i = 0; i < 4; i++) {
      int seg = wid + 4 * i;          // 0..15
      int isB = seg >> 3;
      int s = seg & 7;
      int q = s >> 1, hv = s & 1;     // k-quad, m-half
      const u16* gsrc = isB ? Bt : A;
      int grow = (isB ? col0 : row0) + hv * 64 + lane;
      const u16* g = gsrc + (size_t)grow * K + (k0 + q * 8);
      u16* l = (isB ? Bsm : Asm) + (q * 128 + hv * 64) * 8;  // wave-uniform
      async_ld16(g, l);
    }
    __syncthreads();  // drains vmcnt -> LDS ready
    bf16x8 af[4], bfr[4];
#pragma unroll
    for (int mt = 0; mt < 4; mt++)
      af[mt] = *(const bf16x8*)(Asm + (quad * 128 + wm * 64 + mt * 16 + l15) * 8);
#pragma unroll
    for (int nt = 0; nt < 4; nt++)
      bfr[nt] = *(const bf16x8*)(Bsm + (quad * 128 + wn * 64 + nt * 16 + l15) * 8);
#pragma unroll
    for (int mt = 0; mt < 4; mt++)
#pragma unroll
      for (int nt = 0; nt < 4; nt++)
        acc[mt][nt] = __builtin_amdgcn_mfma_f32_16x16x32_bf16(af[mt], bfr[nt], acc[mt][nt], 0, 0, 0);
  }

#pragma unroll
  for (int mt = 0; mt < 4; mt++)
#pragma unroll
    for (int r = 0; r < 4; r++) {
      int row = row0 + wm * 64 + mt * 16 + quad * 4 + r;
#pragma unroll
      for (int nt = 0; nt < 4; nt++) {
        int col = col0 + wn * 64 + nt * 16 + l15;
        if (outf) {
          ((float*)C)[(size_t)row * N + col] = acc[mt][nt][r];
        } else {
          ((u16*)C)[(size_t)row * N + col] = f2bf(acc[mt][nt][r]);
        }
      }
    }
}

// Flash attention. 256 thr = 4 waves, wave owns 32 q rows; KVBLK=128 (round-0
// geometry: 32 tiles, 4 barriers/tile — the KVBLK=64 variant regressed).
// KVb holds K during QK^T, then V^T (from pre-transposed Vt) for PV.
// V^T is staged via async 16B loads issued right after the K-reads-done
// barrier, so V latency hides under the whole softmax phase.
__global__ __launch_bounds__(256, 2) void attn(
    const u16* __restrict__ Q,   // [MROWS][HIDDEN] bf16
    const u16* __restrict__ Kv,  // [KVLEN][HIDDEN] bf16
    const u16* __restrict__ Vt,  // [HEADS*HDIM][KVLEN] bf16 (per-head V^T)
    u16* __restrict__ O) {       // [MROWS][HIDDEN] bf16
  __shared__ __align__(16) u16 KVb[16 * 1024];  // K: [d/8 16][kv 128][8d]; V: [kv/8 16][d 128][8kv]
  __shared__ __align__(16) u16 Pb[128 * 136];   // [q 128][128 + 8 pad]
  const int tid = threadIdx.x;
  const int wid = tid >> 6, lane = tid & 63;
  const int quad = lane >> 4, l15 = lane & 15;
  // XCD swizzle: 128 consecutive swizzled ids = 2 heads -> K+V slice 4MB = one L2
  const int lin = blockIdx.x + (blockIdx.y << 3) + (blockIdx.z << 7);
  const int swz = ((lin & 7) << 7) + (lin >> 3);
  const int h = swz >> 6, b = (swz >> 3) & 7, qt = swz & 7;
  const int qrow0 = b * QLEN + qt * 128;
  const int hcol = h * HDIM;
  const float cexp = 0.08838834764831845f * 1.4426950408889634f;  // SCALE*log2(e)

  bf16x8 qf[2][4];
#pragma unroll
  for (int mt = 0; mt < 2; mt++)
#pragma unroll
    for (int ks = 0; ks < 4; ks++) {
      int row = qrow0 + wid * 32 + mt * 16 + l15;
      qf[mt][ks] = *(const bf16x8*)(Q + (size_t)row * HIDDEN + hcol + ks * 32 + quad * 8);
    }

  f32x4 o[2][8];
#pragma unroll
  for (int mt = 0; mt < 2; mt++)
#pragma unroll
    for (int dt = 0; dt < 8; dt++) o[mt][dt] = (f32x4){0.f, 0.f, 0.f, 0.f};
  float mrun[2][4], lrun[2][4];
#pragma unroll
  for (int mt = 0; mt < 2; mt++)
#pragma unroll
    for (int r = 0; r < 4; r++) { mrun[mt][r] = -INFINITY; lrun[mt][r] = 0.f; }

  for (int kv0 = 0; kv0 < KVLEN; kv0 += 128) {
    __syncthreads();  // (a) prev PV reads of KVb/Pb done
#pragma unroll
    for (int i = 0; i < 8; i++) {
      int seg = wid + 4 * i;        // 0..31
      int ch = seg >> 1, sh = seg & 1;
      int kvr = kv0 + sh * 64 + lane;
      const u16* g = Kv + (size_t)kvr * HIDDEN + hcol + ch * 8;
      async_ld16(g, KVb + (ch * 128 + sh * 64) * 8);  // wave-uniform dest
    }
    __syncthreads();  // (b) K ready

    f32x4 sc[2][8];
#pragma unroll
    for (int mt = 0; mt < 2; mt++)
#pragma unroll
      for (int nt = 0; nt < 8; nt++) sc[mt][nt] = (f32x4){0.f, 0.f, 0.f, 0.f};
#pragma unroll
    for (int ks = 0; ks < 4; ks++) {
      bf16x8 kf[8];
#pragma unroll
      for (int nt = 0; nt < 8; nt++)
        kf[nt] = *(const bf16x8*)(KVb + ((ks * 4 + quad) * 128 + nt * 16 + l15) * 8);
#pragma unroll
      for (int mt = 0; mt < 2; mt++)
#pragma unroll
        for (int nt = 0; nt < 8; nt++)
          sc[mt][nt] = __builtin_amdgcn_mfma_f32_16x16x32_bf16(qf[mt][ks], kf[nt], sc[mt][nt], 0, 0, 0);
    }
    __syncthreads();  // (c) K reads done -> KVb reusable for V

    // Issue V^T stage now (async into KVb); drains at (d). Latency hides
    // under softmax below, which touches only registers/shuffles/Pb.
#pragma unroll
    for (int i = 0; i < 8; i++) {
      int seg = wid + 4 * i;        // 0..31
      int ch = seg >> 1, dh = seg & 1;   // kv-octet, d-half
      int d = dh * 64 + lane;
      const u16* g = Vt + ((size_t)hcol + d) * KVLEN + kv0 + ch * 8;
      async_ld16(g, KVb + (ch * 128 + dh * 64) * 8);  // wave-uniform dest
    }

#pragma unroll
    for (int mt = 0; mt < 2; mt++) {
#pragma unroll
      for (int r = 0; r < 4; r++) {
        float mx = sc[mt][0][r];
#pragma unroll
        for (int nt = 1; nt < 8; nt++) mx = fmaxf(mx, sc[mt][nt][r]);
#pragma unroll
        for (int off = 1; off < 16; off <<= 1) mx = fmaxf(mx, __shfl_xor(mx, off, 64));
        float mn = fmaxf(mrun[mt][r], mx);
        float al = __builtin_amdgcn_exp2f((mrun[mt][r] - mn) * cexp);
        mrun[mt][r] = mn;
        float mc = mn * cexp;
        float ps = 0.f;
#pragma unroll
        for (int nt = 0; nt < 8; nt++) {
          float p = __builtin_amdgcn_exp2f(sc[mt][nt][r] * cexp - mc);
          sc[mt][nt][r] = p;
          ps += p;
        }
#pragma unroll
        for (int off = 1; off < 16; off <<= 1) ps += __shfl_xor(ps, off, 64);
        lrun[mt][r] = lrun[mt][r] * al + ps;
#pragma unroll
        for (int dt = 0; dt < 8; dt++) o[mt][dt][r] *= al;
      }
    }

#pragma unroll
    for (int mt = 0; mt < 2; mt++)
#pragma unroll
      for (int nt = 0; nt < 8; nt++)
#pragma unroll
        for (int r = 0; r < 4; r++) {
          int prow = wid * 32 + mt * 16 + quad * 4 + r;
          Pb[prow * 136 + nt * 16 + l15] = f2bf(sc[mt][nt][r]);
        }
    __syncthreads();  // (d) drains V loads (vmcnt) + P writes visible

#pragma unroll
    for (int ks = 0; ks < 4; ks++) {
      bf16x8 pf[2], vf[8];
#pragma unroll
      for (int mt = 0; mt < 2; mt++)
        pf[mt] = *(const bf16x8*)(Pb + (wid * 32 + mt * 16 + l15) * 136 + ks * 32 + quad * 8);
#pragma unroll
      for (int dt = 0; dt < 8; dt++)
        vf[dt] = *(const bf16x8*)(KVb + ((ks * 4 + quad) * 128 + dt * 16 + l15) * 8);
#pragma unroll
      for (int mt = 0; mt < 2; mt++)
#pragma unroll
        for (int dt = 0; dt < 8; dt++)
          o[mt][dt] = __builtin_amdgcn_mfma_f32_16x16x32_bf16(pf[mt], vf[dt], o[mt][dt], 0, 0, 0);
    }
  }

#pragma unroll
  for (int mt = 0; mt < 2; mt++)
#pragma unroll
    for (int r = 0; r < 4; r++) {
      float inv = 1.0f / lrun[mt][r];
      int row = qrow0 + wid * 32 + mt * 16 + quad * 4 + r;
#pragma unroll
      for (int dt = 0; dt < 8; dt++) {
        int col = hcol + dt * 16 + l15;
        O[(size_t)row * HIDDEN + col] = f2bf(o[mt][dt][r] * inv);
      }
    }
}

extern "C" void kernel_launch(void* const* d_in, const int* in_sizes, int n_in,
                              void* d_out, int out_size, void* d_ws, size_t ws_size,
                              hipStream_t stream) {
  const float* query = (const float*)d_in[0];
  const float* kv_k  = (const float*)d_in[1];
  const float* kv_v  = (const float*)d_in[2];
  const float* Wq    = (const float*)d_in[3];
  const float* Wo    = (const float*)d_in[4];
  float* out = (float*)d_out;

  const long NQ = (long)MROWS * HIDDEN;   // 16.78M
  const long NK = (long)KVLEN * HIDDEN;   // 8.39M
  const long NW = (long)HIDDEN * HIDDEN;  // 4.19M

  dim3 blk(256);

  // ws (u16): [convQ NQ][convK NK][Vt NK][convWq NW][convWo NW][Qws NQ]; Ows aliases convQ.
  u16* convQ  = (u16*)d_ws;
  u16* convK  = convQ + NQ;
  u16* Vtb    = convK + NK;
  u16* convWq = Vtb + NK;
  u16* convWo = convWq + NW;
  u16* Qws    = convWo + NW;
  u16* Ows    = convQ;  // convQ dead after gemm1

  convert_bf16<<<dim3((NQ / 8 + 255) / 256), blk, 0, stream>>>(query, convQ,  NQ);
  convert_bf16<<<dim3((NK / 8 + 255) / 256), blk, 0, stream>>>(kv_k,  convK,  NK);
  transpose_v<<<dim3(KVLEN / 128, HEADS), blk, 0, stream>>>(kv_v, Vtb);
  convert_bf16<<<dim3((NW / 8 + 255) / 256), blk, 0, stream>>>(Wq,    convWq, NW);
  convert_bf16<<<dim3((NW / 8 + 255) / 256), blk, 0, stream>>>(Wo,    convWo, NW);

  gemm_bt<<<dim3(HIDDEN / 128, MROWS / 128), blk, 0, stream>>>(convQ, convWq, Qws, MROWS, HIDDEN, HIDDEN, 0);
  attn<<<dim3(QLEN / 128, HEADS, BQ), blk, 0, stream>>>(Qws, convK, Vtb, Ows);
  gemm_bt<<<dim3(HIDDEN / 128, MROWS / 128), blk, 0, stream>>>(Ows, convWo, out, MROWS, HIDDEN, HIDDEN, 1);
}

// Round 4
// 1042.435 us; speedup vs baseline: 1.2422x; 1.0052x over previous
//
#include <hip/hip_runtime.h>

#define HIDDEN 2048
#define HEADS 16
#define HDIM 128
#define BQ 8
#define QLEN 1024
#define KVLEN 4096
#define MROWS (BQ * QLEN)  // 8192

typedef __bf16 bf16x8 __attribute__((ext_vector_type(8)));
typedef float f32x4 __attribute__((ext_vector_type(4)));
typedef unsigned short u16;
typedef u16 u16x8 __attribute__((ext_vector_type(8)));
typedef float f32x8v __attribute__((ext_vector_type(8)));

// fp32 -> bf16 bits, round-to-nearest-even
__device__ __forceinline__ u16 f2bf(float f) {
  union { float f; unsigned u; } v; v.f = f;
  unsigned r = (v.u + 0x7FFFu + ((v.u >> 16) & 1u)) >> 16;
  return (u16)r;
}

// async global->LDS, 16B per lane; LDS dest = wave-uniform base + lane*16
__device__ __forceinline__ void async_ld16(const void* g, void* l) {
  __builtin_amdgcn_global_load_lds(
      (const __attribute__((address_space(1))) void*)g,
      (__attribute__((address_space(3))) void*)l, 16, 0, 0);
}

// fp32 -> bf16 narrowing copy
__global__ void convert_bf16(const float* __restrict__ src, u16* __restrict__ dst,
                             long n) {
  long base = ((long)blockIdx.x * blockDim.x + threadIdx.x) * 8;
  long stride = (long)gridDim.x * blockDim.x * 8;
  for (long i = base; i < n; i += stride) {
    f32x8v s = *(const f32x8v*)(src + i);
    u16x8 o;
#pragma unroll
    for (int j = 0; j < 8; j++) o[j] = f2bf(s[j]);
    *(u16x8*)(dst + i) = o;
  }
}

// V fp32 [KVLEN][HIDDEN] -> Vt bf16 [HEADS*HDIM][KVLEN] (per-head transpose),
// fused with bf16 conversion. Done ONCE: V is shared across batch and q-tiles.
__global__ __launch_bounds__(256) void transpose_v(const float* __restrict__ V,
                                                   u16* __restrict__ Vt) {
  __shared__ u16 T[128][129];
  const int kv0 = blockIdx.x * 128;
  const int h = blockIdx.y;
  const int tid = threadIdx.x;
#pragma unroll
  for (int p = 0; p < 8; p++) {
    int idx = p * 2048 + tid * 8;
    int r = idx >> 7, c = idx & 127;  // kv-row, d-col
    f32x8v s = *(const f32x8v*)(V + (size_t)(kv0 + r) * HIDDEN + h * HDIM + c);
#pragma unroll
    for (int j = 0; j < 8; j++) T[r][c + j] = f2bf(s[j]);
  }
  __syncthreads();
#pragma unroll
  for (int p = 0; p < 8; p++) {
    int idx = p * 2048 + tid * 8;
    int d = idx >> 7, kv = idx & 127;
    u16x8 o;
#pragma unroll
    for (int j = 0; j < 8; j++) o[j] = T[kv + j][d];
    *(u16x8*)(Vt + ((size_t)h * HDIM + d) * KVLEN + kv0 + kv) = o;
  }
}

// C[M][N] = A[M][K] @ Bt[N][K]^T  (bf16 in, fp32 accum; out bf16 or fp32)
// 128x128 tile, 4 waves (2x2), each wave 64x64 = 4x4 frags of 16x16x32 MFMA.
__global__ __launch_bounds__(256) void gemm_bt(
    const u16* __restrict__ A, const u16* __restrict__ Bt, void* __restrict__ C,
    int M, int N, int K, int outf) {
  __shared__ __align__(16) u16 Asm[4 * 128 * 8];
  __shared__ __align__(16) u16 Bsm[4 * 128 * 8];
  const int tid = threadIdx.x;
  const int wid = tid >> 6, lane = tid & 63;
  const int quad = lane >> 4, l15 = lane & 15;
  const int wm = wid >> 1, wn = wid & 1;
  // nwg = 1024 (16 x 64), divisible by 8 -> simple XCD swizzle is bijective
  const int lin = blockIdx.y * gridDim.x + blockIdx.x;
  const int cpx = (gridDim.x * gridDim.y) >> 3;
  const int swz = (lin & 7) * cpx + (lin >> 3);
  const int by = swz / gridDim.x;
  const int bx = swz - by * gridDim.x;
  const int row0 = by * 128;
  const int col0 = bx * 128;

  f32x4 acc[4][4];
#pragma unroll
  for (int i = 0; i < 4; i++)
#pragma unroll
    for (int j = 0; j < 4; j++) acc[i][j] = (f32x4){0.f, 0.f, 0.f, 0.f};

  for (int k0 = 0; k0 < K; k0 += 32) {
    __syncthreads();  // prev iter's ds_reads done before overwrite
#pragma unroll
    for (int i = 0; i < 4; i++) {
      int seg = wid + 4 * i;          // 0..15
      int isB = seg >> 3;
      int s = seg & 7;
      int q = s >> 1, hv = s & 1;     // k-quad, m-half
      const u16* gsrc = isB ? Bt : A;
      int grow = (isB ? col0 : row0) + hv * 64 + lane;
      const u16* g = gsrc + (size_t)grow * K + (k0 + q * 8);
      u16* l = (isB ? Bsm : Asm) + (q * 128 + hv * 64) * 8;  // wave-uniform
      async_ld16(g, l);
    }
    __syncthreads();  // drains vmcnt -> LDS ready
    bf16x8 af[4], bfr[4];
#pragma unroll
    for (int mt = 0; mt < 4; mt++)
      af[mt] = *(const bf16x8*)(Asm + (quad * 128 + wm * 64 + mt * 16 + l15) * 8);
#pragma unroll
    for (int nt = 0; nt < 4; nt++)
      bfr[nt] = *(const bf16x8*)(Bsm + (quad * 128 + wn * 64 + nt * 16 + l15) * 8);
#pragma unroll
    for (int mt = 0; mt < 4; mt++)
#pragma unroll
      for (int nt = 0; nt < 4; nt++)
        acc[mt][nt] = __builtin_amdgcn_mfma_f32_16x16x32_bf16(af[mt], bfr[nt], acc[mt][nt], 0, 0, 0);
  }

#pragma unroll
  for (int mt = 0; mt < 4; mt++)
#pragma unroll
    for (int r = 0; r < 4; r++) {
      int row = row0 + wm * 64 + mt * 16 + quad * 4 + r;
#pragma unroll
      for (int nt = 0; nt < 4; nt++) {
        int col = col0 + wn * 64 + nt * 16 + l15;
        if (outf) {
          ((float*)C)[(size_t)row * N + col] = acc[mt][nt][r];
        } else {
          ((u16*)C)[(size_t)row * N + col] = f2bf(acc[mt][nt][r]);
        }
      }
    }
}

// Flash attention. 512 thr = 8 waves over a 128-q-row tile; wave owns 16 rows.
// Same LDS (66KB -> 2 blocks/CU) but 16 waves/CU = 4/SIMD (was 8/CU = 2/SIMD):
// pure TLP gain for the latency-bound phases. KVBLK=128, 4 barriers/tile.
// KVb holds K during QK^T, then V^T (pre-transposed Vt) for PV; V^T staged
// async right after the K-reads-done barrier -> latency hides under softmax.
__global__ __launch_bounds__(512, 4) void attn(
    const u16* __restrict__ Q,   // [MROWS][HIDDEN] bf16
    const u16* __restrict__ Kv,  // [KVLEN][HIDDEN] bf16
    const u16* __restrict__ Vt,  // [HEADS*HDIM][KVLEN] bf16 (per-head V^T)
    u16* __restrict__ O) {       // [MROWS][HIDDEN] bf16
  __shared__ __align__(16) u16 KVb[16 * 1024];  // K: [d/8 16][kv 128][8d]; V: [kv/8 16][d 128][8kv]
  __shared__ __align__(16) u16 Pb[128 * 136];   // [q 128][128 + 8 pad]
  const int tid = threadIdx.x;
  const int wid = tid >> 6, lane = tid & 63;    // wid 0..7
  const int quad = lane >> 4, l15 = lane & 15;
  // XCD swizzle: 128 consecutive swizzled ids = 2 heads -> K+V slice 4MB = one L2
  const int lin = blockIdx.x + (blockIdx.y << 3) + (blockIdx.z << 7);
  const int swz = ((lin & 7) << 7) + (lin >> 3);
  const int h = swz >> 6, b = (swz >> 3) & 7, qt = swz & 7;
  const int qrow0 = b * QLEN + qt * 128;
  const int hcol = h * HDIM;
  const float cexp = 0.08838834764831845f * 1.4426950408889634f;  // SCALE*log2(e)

  bf16x8 qf[4];
#pragma unroll
  for (int ks = 0; ks < 4; ks++) {
    int row = qrow0 + wid * 16 + l15;
    qf[ks] = *(const bf16x8*)(Q + (size_t)row * HIDDEN + hcol + ks * 32 + quad * 8);
  }

  f32x4 o[8];
#pragma unroll
  for (int dt = 0; dt < 8; dt++) o[dt] = (f32x4){0.f, 0.f, 0.f, 0.f};
  float mrun[4], lrun[4];
#pragma unroll
  for (int r = 0; r < 4; r++) { mrun[r] = -INFINITY; lrun[r] = 0.f; }

  for (int kv0 = 0; kv0 < KVLEN; kv0 += 128) {
    __syncthreads();  // (a) prev PV reads of KVb/Pb done
#pragma unroll
    for (int i = 0; i < 4; i++) {
      int seg = wid + 8 * i;        // 0..31
      int ch = seg >> 1, sh = seg & 1;
      int kvr = kv0 + sh * 64 + lane;
      const u16* g = Kv + (size_t)kvr * HIDDEN + hcol + ch * 8;
      async_ld16(g, KVb + (ch * 128 + sh * 64) * 8);  // wave-uniform dest
    }
    __syncthreads();  // (b) K ready

    f32x4 sc[8];
#pragma unroll
    for (int nt = 0; nt < 8; nt++) sc[nt] = (f32x4){0.f, 0.f, 0.f, 0.f};
#pragma unroll
    for (int ks = 0; ks < 4; ks++) {
      bf16x8 kf[8];
#pragma unroll
      for (int nt = 0; nt < 8; nt++)
        kf[nt] = *(const bf16x8*)(KVb + ((ks * 4 + quad) * 128 + nt * 16 + l15) * 8);
#pragma unroll
      for (int nt = 0; nt < 8; nt++)
        sc[nt] = __builtin_amdgcn_mfma_f32_16x16x32_bf16(qf[ks], kf[nt], sc[nt], 0, 0, 0);
    }
    __syncthreads();  // (c) K reads done -> KVb reusable for V

    // Issue V^T stage now (async into KVb); drains at (d). Latency hides
    // under softmax below, which touches only registers/shuffles/Pb.
#pragma unroll
    for (int i = 0; i < 4; i++) {
      int seg = wid + 8 * i;             // 0..31
      int ch = seg >> 1, dh = seg & 1;   // kv-octet, d-half
      int d = dh * 64 + lane;
      const u16* g = Vt + ((size_t)hcol + d) * KVLEN + kv0 + ch * 8;
      async_ld16(g, KVb + (ch * 128 + dh * 64) * 8);  // wave-uniform dest
    }

#pragma unroll
    for (int r = 0; r < 4; r++) {
      float mx = sc[0][r];
#pragma unroll
      for (int nt = 1; nt < 8; nt++) mx = fmaxf(mx, sc[nt][r]);
#pragma unroll
      for (int off = 1; off < 16; off <<= 1) mx = fmaxf(mx, __shfl_xor(mx, off, 64));
      float mn = fmaxf(mrun[r], mx);
      float al = __builtin_amdgcn_exp2f((mrun[r] - mn) * cexp);
      mrun[r] = mn;
      float mc = mn * cexp;
      float ps = 0.f;
#pragma unroll
      for (int nt = 0; nt < 8; nt++) {
        float p = __builtin_amdgcn_exp2f(sc[nt][r] * cexp - mc);
        sc[nt][r] = p;
        ps += p;
      }
#pragma unroll
      for (int off = 1; off < 16; off <<= 1) ps += __shfl_xor(ps, off, 64);
      lrun[r] = lrun[r] * al + ps;
#pragma unroll
      for (int dt = 0; dt < 8; dt++) o[dt][r] *= al;
    }

#pragma unroll
    for (int nt = 0; nt < 8; nt++)
#pragma unroll
      for (int r = 0; r < 4; r++) {
        int prow = wid * 16 + quad * 4 + r;
        Pb[prow * 136 + nt * 16 + l15] = f2bf(sc[nt][r]);
      }
    __syncthreads();  // (d) drains V loads (vmcnt) + P writes visible

#pragma unroll
    for (int ks = 0; ks < 4; ks++) {
      bf16x8 pf, vf[8];
      pf = *(const bf16x8*)(Pb + (wid * 16 + l15) * 136 + ks * 32 + quad * 8);
#pragma unroll
      for (int dt = 0; dt < 8; dt++)
        vf[dt] = *(const bf16x8*)(KVb + ((ks * 4 + quad) * 128 + dt * 16 + l15) * 8);
#pragma unroll
      for (int dt = 0; dt < 8; dt++)
        o[dt] = __builtin_amdgcn_mfma_f32_16x16x32_bf16(pf, vf[dt], o[dt], 0, 0, 0);
    }
  }

#pragma unroll
  for (int r = 0; r < 4; r++) {
    float inv = 1.0f / lrun[r];
    int row = qrow0 + wid * 16 + quad * 4 + r;
#pragma unroll
    for (int dt = 0; dt < 8; dt++) {
      int col = hcol + dt * 16 + l15;
      O[(size_t)row * HIDDEN + col] = f2bf(o[dt][r] * inv);
    }
  }
}

extern "C" void kernel_launch(void* const* d_in, const int* in_sizes, int n_in,
                              void* d_out, int out_size, void* d_ws, size_t ws_size,
                              hipStream_t stream) {
  const float* query = (const float*)d_in[0];
  const float* kv_k  = (const float*)d_in[1];
  const float* kv_v  = (const float*)d_in[2];
  const float* Wq    = (const float*)d_in[3];
  const float* Wo    = (const float*)d_in[4];
  float* out = (float*)d_out;

  const long NQ = (long)MROWS * HIDDEN;   // 16.78M
  const long NK = (long)KVLEN * HIDDEN;   // 8.39M
  const long NW = (long)HIDDEN * HIDDEN;  // 4.19M

  dim3 blk(256);

  // ws (u16): [convQ NQ][convK NK][Vt NK][convWq NW][convWo NW][Qws NQ]; Ows aliases convQ.
  u16* convQ  = (u16*)d_ws;
  u16* convK  = convQ + NQ;
  u16* Vtb    = convK + NK;
  u16* convWq = Vtb + NK;
  u16* convWo = convWq + NW;
  u16* Qws    = convWo + NW;
  u16* Ows    = convQ;  // convQ dead after gemm1

  convert_bf16<<<dim3((NQ / 8 + 255) / 256), blk, 0, stream>>>(query, convQ,  NQ);
  convert_bf16<<<dim3((NK / 8 + 255) / 256), blk, 0, stream>>>(kv_k,  convK,  NK);
  transpose_v<<<dim3(KVLEN / 128, HEADS), blk, 0, stream>>>(kv_v, Vtb);
  convert_bf16<<<dim3((NW / 8 + 255) / 256), blk, 0, stream>>>(Wq,    convWq, NW);
  convert_bf16<<<dim3((NW / 8 + 255) / 256), blk, 0, stream>>>(Wo,    convWo, NW);

  gemm_bt<<<dim3(HIDDEN / 128, MROWS / 128), blk, 0, stream>>>(convQ, convWq, Qws, MROWS, HIDDEN, HIDDEN, 0);
  attn<<<dim3(QLEN / 128, HEADS, BQ), dim3(512), 0, stream>>>(Qws, convK, Vtb, Ows);
  gemm_bt<<<dim3(HIDDEN / 128, MROWS / 128), blk, 0, stream>>>(Ows, convWo, out, MROWS, HIDDEN, HIDDEN, 1);
}

// Round 5
// 956.149 us; speedup vs baseline: 1.3543x; 1.0902x over previous
//
#include <hip/hip_runtime.h>

#define HIDDEN 2048
#define HEADS 16
#define HDIM 128
#define BQ 8
#define QLEN 1024
#define KVLEN 4096
#define MROWS (BQ * QLEN)  // 8192

typedef __bf16 bf16x8 __attribute__((ext_vector_type(8)));
typedef float f32x4 __attribute__((ext_vector_type(4)));
typedef unsigned short u16;
typedef u16 u16x8 __attribute__((ext_vector_type(8)));
typedef float f32x8v __attribute__((ext_vector_type(8)));

// async global->LDS, 16B per lane; LDS dest = wave-uniform base + lane*16
__device__ __forceinline__ void async_ld16(const void* g, void* l) {
  __builtin_amdgcn_global_load_lds(
      (const __attribute__((address_space(1))) void*)g,
      (__attribute__((address_space(3))) void*)l, 16, 0, 0);
}

// fp32 -> bf16 narrowing copy (native cast = single v_cvt per element, m240)
__global__ void convert_bf16(const float* __restrict__ src, u16* __restrict__ dst,
                             long n) {
  long base = ((long)blockIdx.x * blockDim.x + threadIdx.x) * 8;
  long stride = (long)gridDim.x * blockDim.x * 8;
  for (long i = base; i < n; i += stride) {
    f32x8v s = *(const f32x8v*)(src + i);
    bf16x8 o;
#pragma unroll
    for (int j = 0; j < 8; j++) o[j] = (__bf16)s[j];
    *(bf16x8*)(dst + i) = o;
  }
}

// V fp32 [KVLEN][HIDDEN] -> Vt bf16 [HEADS*HDIM][KVLEN] (per-head transpose),
// fused with bf16 conversion. Done ONCE: V is shared across batch and q-tiles.
__global__ __launch_bounds__(256) void transpose_v(const float* __restrict__ V,
                                                   u16* __restrict__ Vt) {
  __shared__ __bf16 T[128][129];
  const int kv0 = blockIdx.x * 128;
  const int h = blockIdx.y;
  const int tid = threadIdx.x;
#pragma unroll
  for (int p = 0; p < 8; p++) {
    int idx = p * 2048 + tid * 8;
    int r = idx >> 7, c = idx & 127;  // kv-row, d-col
    f32x8v s = *(const f32x8v*)(V + (size_t)(kv0 + r) * HIDDEN + h * HDIM + c);
#pragma unroll
    for (int j = 0; j < 8; j++) T[r][c + j] = (__bf16)s[j];
  }
  __syncthreads();
#pragma unroll
  for (int p = 0; p < 8; p++) {
    int idx = p * 2048 + tid * 8;
    int d = idx >> 7, kv = idx & 127;
    bf16x8 o;
#pragma unroll
    for (int j = 0; j < 8; j++) o[j] = T[kv + j][d];
    *(bf16x8*)(Vt + ((size_t)h * HDIM + d) * KVLEN + kv0 + kv) = o;
  }
}

// C[M][N] = A[M][K] @ Bt[N][K]^T  (bf16 in, fp32 accum; out bf16 or fp32)
// 128x128 tile, 4 waves (2x2), each wave 64x64 = 4x4 frags of 16x16x32 MFMA.
__global__ __launch_bounds__(256) void gemm_bt(
    const u16* __restrict__ A, const u16* __restrict__ Bt, void* __restrict__ C,
    int M, int N, int K, int outf) {
  __shared__ __align__(16) u16 Asm[4 * 128 * 8];
  __shared__ __align__(16) u16 Bsm[4 * 128 * 8];
  const int tid = threadIdx.x;
  const int wid = tid >> 6, lane = tid & 63;
  const int quad = lane >> 4, l15 = lane & 15;
  const int wm = wid >> 1, wn = wid & 1;
  // nwg = 1024 (16 x 64), divisible by 8 -> simple XCD swizzle is bijective
  const int lin = blockIdx.y * gridDim.x + blockIdx.x;
  const int cpx = (gridDim.x * gridDim.y) >> 3;
  const int swz = (lin & 7) * cpx + (lin >> 3);
  const int by = swz / gridDim.x;
  const int bx = swz - by * gridDim.x;
  const int row0 = by * 128;
  const int col0 = bx * 128;

  f32x4 acc[4][4];
#pragma unroll
  for (int i = 0; i < 4; i++)
#pragma unroll
    for (int j = 0; j < 4; j++) acc[i][j] = (f32x4){0.f, 0.f, 0.f, 0.f};

  for (int k0 = 0; k0 < K; k0 += 32) {
    __syncthreads();  // prev iter's ds_reads done before overwrite
#pragma unroll
    for (int i = 0; i < 4; i++) {
      int seg = wid + 4 * i;          // 0..15
      int isB = seg >> 3;
      int s = seg & 7;
      int q = s >> 1, hv = s & 1;     // k-quad, m-half
      const u16* gsrc = isB ? Bt : A;
      int grow = (isB ? col0 : row0) + hv * 64 + lane;
      const u16* g = gsrc + (size_t)grow * K + (k0 + q * 8);
      u16* l = (isB ? Bsm : Asm) + (q * 128 + hv * 64) * 8;  // wave-uniform
      async_ld16(g, l);
    }
    __syncthreads();  // drains vmcnt -> LDS ready
    bf16x8 af[4], bfr[4];
#pragma unroll
    for (int mt = 0; mt < 4; mt++)
      af[mt] = *(const bf16x8*)(Asm + (quad * 128 + wm * 64 + mt * 16 + l15) * 8);
#pragma unroll
    for (int nt = 0; nt < 4; nt++)
      bfr[nt] = *(const bf16x8*)(Bsm + (quad * 128 + wn * 64 + nt * 16 + l15) * 8);
#pragma unroll
    for (int mt = 0; mt < 4; mt++)
#pragma unroll
      for (int nt = 0; nt < 4; nt++)
        acc[mt][nt] = __builtin_amdgcn_mfma_f32_16x16x32_bf16(af[mt], bfr[nt], acc[mt][nt], 0, 0, 0);
  }

#pragma unroll
  for (int mt = 0; mt < 4; mt++)
#pragma unroll
    for (int r = 0; r < 4; r++) {
      int row = row0 + wm * 64 + mt * 16 + quad * 4 + r;
#pragma unroll
      for (int nt = 0; nt < 4; nt++) {
        int col = col0 + wn * 64 + nt * 16 + l15;
        if (outf) {
          ((float*)C)[(size_t)row * N + col] = acc[mt][nt][r];
        } else {
          ((__bf16*)C)[(size_t)row * N + col] = (__bf16)acc[mt][nt][r];
        }
      }
    }
}

// Flash attention. 512 thr = 8 waves over a 128-q-row tile; wave owns 16 rows.
// LDS 66KB -> 2 blocks/CU = 16 waves/CU (4/SIMD). KVBLK=128, 4 barriers/tile.
// Round-5: native bf16 casts (1 VALU op vs 4-5 for manual f2bf), defer-max
// rescale skip (T13), and halved transient kf/vf pressure to kill the
// round-4 scratch spills (WRITE_SIZE 77->207MB at VGPR=64 was the evidence).
__global__ __launch_bounds__(512, 4) void attn(
    const u16* __restrict__ Q,   // [MROWS][HIDDEN] bf16
    const u16* __restrict__ Kv,  // [KVLEN][HIDDEN] bf16
    const u16* __restrict__ Vt,  // [HEADS*HDIM][KVLEN] bf16 (per-head V^T)
    u16* __restrict__ O) {       // [MROWS][HIDDEN] bf16
  __shared__ __align__(16) u16 KVb[16 * 1024];   // K: [d/8 16][kv 128][8d]; V: [kv/8 16][d 128][8kv]
  __shared__ __align__(16) __bf16 Pb[128 * 136]; // [q 128][128 + 8 pad]
  const int tid = threadIdx.x;
  const int wid = tid >> 6, lane = tid & 63;    // wid 0..7
  const int quad = lane >> 4, l15 = lane & 15;
  // XCD swizzle: 128 consecutive swizzled ids = 2 heads -> K+V slice 4MB = one L2
  const int lin = blockIdx.x + (blockIdx.y << 3) + (blockIdx.z << 7);
  const int swz = ((lin & 7) << 7) + (lin >> 3);
  const int h = swz >> 6, b = (swz >> 3) & 7, qt = swz & 7;
  const int qrow0 = b * QLEN + qt * 128;
  const int hcol = h * HDIM;
  const float cexp = 0.08838834764831845f * 1.4426950408889634f;  // SCALE*log2(e)

  bf16x8 qf[4];
#pragma unroll
  for (int ks = 0; ks < 4; ks++) {
    int row = qrow0 + wid * 16 + l15;
    qf[ks] = *(const bf16x8*)(Q + (size_t)row * HIDDEN + hcol + ks * 32 + quad * 8);
  }

  f32x4 o[8];
#pragma unroll
  for (int dt = 0; dt < 8; dt++) o[dt] = (f32x4){0.f, 0.f, 0.f, 0.f};
  float mrun[4], lrun[4];
#pragma unroll
  for (int r = 0; r < 4; r++) { mrun[r] = -INFINITY; lrun[r] = 0.f; }

  for (int kv0 = 0; kv0 < KVLEN; kv0 += 128) {
    __syncthreads();  // (a) prev PV reads of KVb/Pb done
#pragma unroll
    for (int i = 0; i < 4; i++) {
      int seg = wid + 8 * i;        // 0..31
      int ch = seg >> 1, sh = seg & 1;
      int kvr = kv0 + sh * 64 + lane;
      const u16* g = Kv + (size_t)kvr * HIDDEN + hcol + ch * 8;
      async_ld16(g, KVb + (ch * 128 + sh * 64) * 8);  // wave-uniform dest
    }
    __syncthreads();  // (b) K ready

    f32x4 sc[8];
#pragma unroll
    for (int nt = 0; nt < 8; nt++) sc[nt] = (f32x4){0.f, 0.f, 0.f, 0.f};
#pragma unroll
    for (int ks = 0; ks < 4; ks++) {
#pragma unroll
      for (int hf = 0; hf < 2; hf++) {   // 4-reg batches: halve transient VGPRs
        bf16x8 kf[4];
#pragma unroll
        for (int j = 0; j < 4; j++)
          kf[j] = *(const bf16x8*)(KVb + ((ks * 4 + quad) * 128 + (hf * 4 + j) * 16 + l15) * 8);
#pragma unroll
        for (int j = 0; j < 4; j++)
          sc[hf * 4 + j] = __builtin_amdgcn_mfma_f32_16x16x32_bf16(qf[ks], kf[j], sc[hf * 4 + j], 0, 0, 0);
      }
    }
    __syncthreads();  // (c) K reads done -> KVb reusable for V

    // Issue V^T stage now (async into KVb); drains at (d). Latency hides
    // under softmax below, which touches only registers/shuffles/Pb.
#pragma unroll
    for (int i = 0; i < 4; i++) {
      int seg = wid + 8 * i;             // 0..31
      int ch = seg >> 1, dh = seg & 1;   // kv-octet, d-half
      int d = dh * 64 + lane;
      const u16* g = Vt + ((size_t)hcol + d) * KVLEN + kv0 + ch * 8;
      async_ld16(g, KVb + (ch * 128 + dh * 64) * 8);  // wave-uniform dest
    }

    // --- online softmax with defer-max (T13, THR=8 in raw-score units) ---
    float mx[4];
#pragma unroll
    for (int r = 0; r < 4; r++) {
      float m = sc[0][r];
#pragma unroll
      for (int nt = 1; nt < 8; nt++) m = fmaxf(m, sc[nt][r]);
#pragma unroll
      for (int off = 1; off < 16; off <<= 1) m = fmaxf(m, __shfl_xor(m, off, 64));
      mx[r] = m;
    }
    float gmax = fmaxf(fmaxf(mx[0] - mrun[0], mx[1] - mrun[1]),
                       fmaxf(mx[2] - mrun[2], mx[3] - mrun[3]));
    if (__any(gmax > 8.f)) {   // wave-uniform branch
#pragma unroll
      for (int r = 0; r < 4; r++) {
        float mn = fmaxf(mrun[r], mx[r]);
        float al = __builtin_amdgcn_exp2f((mrun[r] - mn) * cexp);
        mrun[r] = mn;
        lrun[r] *= al;
#pragma unroll
        for (int dt = 0; dt < 8; dt++) o[dt][r] *= al;
      }
    }
#pragma unroll
    for (int r = 0; r < 4; r++) {
      float mc = mrun[r] * cexp;
      float ps = 0.f;
#pragma unroll
      for (int nt = 0; nt < 8; nt++) {
        float p = __builtin_amdgcn_exp2f(sc[nt][r] * cexp - mc);
        sc[nt][r] = p;
        ps += p;
      }
#pragma unroll
      for (int off = 1; off < 16; off <<= 1) ps += __shfl_xor(ps, off, 64);
      lrun[r] += ps;
    }

#pragma unroll
    for (int nt = 0; nt < 8; nt++)
#pragma unroll
      for (int r = 0; r < 4; r++) {
        int prow = wid * 16 + quad * 4 + r;
        Pb[prow * 136 + nt * 16 + l15] = (__bf16)sc[nt][r];  // 1-op hw cvt
      }
    __syncthreads();  // (d) drains V loads (vmcnt) + P writes visible

#pragma unroll
    for (int ks = 0; ks < 4; ks++) {
      bf16x8 pf = *(const bf16x8*)(Pb + (wid * 16 + l15) * 136 + ks * 32 + quad * 8);
#pragma unroll
      for (int hf = 0; hf < 2; hf++) {   // 4-reg batches for vf as well
        bf16x8 vf[4];
#pragma unroll
        for (int j = 0; j < 4; j++)
          vf[j] = *(const bf16x8*)(KVb + ((ks * 4 + quad) * 128 + (hf * 4 + j) * 16 + l15) * 8);
#pragma unroll
        for (int j = 0; j < 4; j++)
          o[hf * 4 + j] = __builtin_amdgcn_mfma_f32_16x16x32_bf16(pf, vf[j], o[hf * 4 + j], 0, 0, 0);
      }
    }
  }

#pragma unroll
  for (int r = 0; r < 4; r++) {
    float inv = 1.0f / lrun[r];
    int row = qrow0 + wid * 16 + quad * 4 + r;
#pragma unroll
    for (int dt = 0; dt < 8; dt++) {
      int col = hcol + dt * 16 + l15;
      ((__bf16*)O)[(size_t)row * HIDDEN + col] = (__bf16)(o[dt][r] * inv);
    }
  }
}

extern "C" void kernel_launch(void* const* d_in, const int* in_sizes, int n_in,
                              void* d_out, int out_size, void* d_ws, size_t ws_size,
                              hipStream_t stream) {
  const float* query = (const float*)d_in[0];
  const float* kv_k  = (const float*)d_in[1];
  const float* kv_v  = (const float*)d_in[2];
  const float* Wq    = (const float*)d_in[3];
  const float* Wo    = (const float*)d_in[4];
  float* out = (float*)d_out;

  const long NQ = (long)MROWS * HIDDEN;   // 16.78M
  const long NK = (long)KVLEN * HIDDEN;   // 8.39M
  const long NW = (long)HIDDEN * HIDDEN;  // 4.19M

  dim3 blk(256);

  // ws (u16): [convQ NQ][convK NK][Vt NK][convWq NW][convWo NW][Qws NQ]; Ows aliases convQ.
  u16* convQ  = (u16*)d_ws;
  u16* convK  = convQ + NQ;
  u16* Vtb    = convK + NK;
  u16* convWq = Vtb + NK;
  u16* convWo = convWq + NW;
  u16* Qws    = convWo + NW;
  u16* Ows    = convQ;  // convQ dead after gemm1

  convert_bf16<<<dim3((NQ / 8 + 255) / 256), blk, 0, stream>>>(query, convQ,  NQ);
  convert_bf16<<<dim3((NK / 8 + 255) / 256), blk, 0, stream>>>(kv_k,  convK,  NK);
  transpose_v<<<dim3(KVLEN / 128, HEADS), blk, 0, stream>>>(kv_v, Vtb);
  convert_bf16<<<dim3((NW / 8 + 255) / 256), blk, 0, stream>>>(Wq,    convWq, NW);
  convert_bf16<<<dim3((NW / 8 + 255) / 256), blk, 0, stream>>>(Wo,    convWo, NW);

  gemm_bt<<<dim3(HIDDEN / 128, MROWS / 128), blk, 0, stream>>>(convQ, convWq, Qws, MROWS, HIDDEN, HIDDEN, 0);
  attn<<<dim3(QLEN / 128, HEADS, BQ), dim3(512), 0, stream>>>(Qws, convK, Vtb, Ows);
  gemm_bt<<<dim3(HIDDEN / 128, MROWS / 128), blk, 0, stream>>>(Ows, convWo, out, MROWS, HIDDEN, HIDDEN, 1);
}

// Round 6
// 879.299 us; speedup vs baseline: 1.4727x; 1.0874x over previous
//
#include <hip/hip_runtime.h>

#define HIDDEN 2048
#define HEADS 16
#define HDIM 128
#define BQ 8
#define QLEN 1024
#define KVLEN 4096
#define MROWS (BQ * QLEN)  // 8192

typedef __bf16 bf16x8 __attribute__((ext_vector_type(8)));
typedef float f32x4 __attribute__((ext_vector_type(4)));
typedef unsigned short u16;
typedef u16 u16x8 __attribute__((ext_vector_type(8)));
typedef float f32x8v __attribute__((ext_vector_type(8)));

// async global->LDS, 16B per lane; LDS dest = wave-uniform base + lane*16
__device__ __forceinline__ void async_ld16(const void* g, void* l) {
  __builtin_amdgcn_global_load_lds(
      (const __attribute__((address_space(1))) void*)g,
      (__attribute__((address_space(3))) void*)l, 16, 0, 0);
}

// fp32 -> bf16 narrowing copy (native cast = single v_cvt per element)
__global__ void convert_bf16(const float* __restrict__ src, u16* __restrict__ dst,
                             long n) {
  long base = ((long)blockIdx.x * blockDim.x + threadIdx.x) * 8;
  long stride = (long)gridDim.x * blockDim.x * 8;
  for (long i = base; i < n; i += stride) {
    f32x8v s = *(const f32x8v*)(src + i);
    bf16x8 o;
#pragma unroll
    for (int j = 0; j < 8; j++) o[j] = (__bf16)s[j];
    *(bf16x8*)(dst + i) = o;
  }
}

// V fp32 [KVLEN][HIDDEN] -> Vt bf16 [HEADS*HDIM][KVLEN] (per-head transpose),
// fused with bf16 conversion. Done ONCE: V is shared across batch and q-tiles.
__global__ __launch_bounds__(256) void transpose_v(const float* __restrict__ V,
                                                   u16* __restrict__ Vt) {
  __shared__ __bf16 T[128][129];
  const int kv0 = blockIdx.x * 128;
  const int h = blockIdx.y;
  const int tid = threadIdx.x;
#pragma unroll
  for (int p = 0; p < 8; p++) {
    int idx = p * 2048 + tid * 8;
    int r = idx >> 7, c = idx & 127;  // kv-row, d-col
    f32x8v s = *(const f32x8v*)(V + (size_t)(kv0 + r) * HIDDEN + h * HDIM + c);
#pragma unroll
    for (int j = 0; j < 8; j++) T[r][c + j] = (__bf16)s[j];
  }
  __syncthreads();
#pragma unroll
  for (int p = 0; p < 8; p++) {
    int idx = p * 2048 + tid * 8;
    int d = idx >> 7, kv = idx & 127;
    bf16x8 o;
#pragma unroll
    for (int j = 0; j < 8; j++) o[j] = T[kv + j][d];
    *(bf16x8*)(Vt + ((size_t)h * HDIM + d) * KVLEN + kv0 + kv) = o;
  }
}

// C[M][N] = A[M][K] @ Bt[N][K]^T  (bf16 in, fp32 accum; out bf16 or fp32)
// 128x128 tile, 4 waves (2x2), each wave 64x64 = 4x4 frags of 16x16x32 MFMA.
// Round-6: BK=64 (was 32) -> half the barrier count; the m97-structure stall
// is the vmcnt(0)+barrier drain, so halving drain frequency amortizes it.
// LDS 32KB still allows the grid-limited 4 blocks/CU.
__global__ __launch_bounds__(256) void gemm_bt(
    const u16* __restrict__ A, const u16* __restrict__ Bt, void* __restrict__ C,
    int M, int N, int K, int outf) {
  __shared__ __align__(16) u16 Asm[8 * 128 * 8];  // [k-octet 8][row 128][8k]
  __shared__ __align__(16) u16 Bsm[8 * 128 * 8];
  const int tid = threadIdx.x;
  const int wid = tid >> 6, lane = tid & 63;
  const int quad = lane >> 4, l15 = lane & 15;
  const int wm = wid >> 1, wn = wid & 1;
  // nwg = 1024 (16 x 64), divisible by 8 -> simple XCD swizzle is bijective
  const int lin = blockIdx.y * gridDim.x + blockIdx.x;
  const int cpx = (gridDim.x * gridDim.y) >> 3;
  const int swz = (lin & 7) * cpx + (lin >> 3);
  const int by = swz / gridDim.x;
  const int bx = swz - by * gridDim.x;
  const int row0 = by * 128;
  const int col0 = bx * 128;

  f32x4 acc[4][4];
#pragma unroll
  for (int i = 0; i < 4; i++)
#pragma unroll
    for (int j = 0; j < 4; j++) acc[i][j] = (f32x4){0.f, 0.f, 0.f, 0.f};

  for (int k0 = 0; k0 < K; k0 += 64) {
    __syncthreads();  // prev iter's ds_reads done before overwrite
#pragma unroll
    for (int i = 0; i < 8; i++) {
      int seg = wid + 4 * i;          // 0..31
      int isB = seg >> 4;
      int s = seg & 15;
      int q = s >> 1, hv = s & 1;     // k-octet 0..7, m-half
      const u16* gsrc = isB ? Bt : A;
      int grow = (isB ? col0 : row0) + hv * 64 + lane;
      const u16* g = gsrc + (size_t)grow * K + (k0 + q * 8);
      u16* l = (isB ? Bsm : Asm) + (q * 128 + hv * 64) * 8;  // wave-uniform
      async_ld16(g, l);
    }
    __syncthreads();  // drains vmcnt -> LDS ready
#pragma unroll
    for (int kk = 0; kk < 2; kk++) {
      bf16x8 af[4], bfr[4];
#pragma unroll
      for (int mt = 0; mt < 4; mt++)
        af[mt] = *(const bf16x8*)(Asm + ((kk * 4 + quad) * 128 + wm * 64 + mt * 16 + l15) * 8);
#pragma unroll
      for (int nt = 0; nt < 4; nt++)
        bfr[nt] = *(const bf16x8*)(Bsm + ((kk * 4 + quad) * 128 + wn * 64 + nt * 16 + l15) * 8);
#pragma unroll
      for (int mt = 0; mt < 4; mt++)
#pragma unroll
        for (int nt = 0; nt < 4; nt++)
          acc[mt][nt] = __builtin_amdgcn_mfma_f32_16x16x32_bf16(af[mt], bfr[nt], acc[mt][nt], 0, 0, 0);
    }
  }

#pragma unroll
  for (int mt = 0; mt < 4; mt++)
#pragma unroll
    for (int r = 0; r < 4; r++) {
      int row = row0 + wm * 64 + mt * 16 + quad * 4 + r;
#pragma unroll
      for (int nt = 0; nt < 4; nt++) {
        int col = col0 + wn * 64 + nt * 16 + l15;
        if (outf) {
          ((float*)C)[(size_t)row * N + col] = acc[mt][nt][r];
        } else {
          ((__bf16*)C)[(size_t)row * N + col] = (__bf16)acc[mt][nt][r];
        }
      }
    }
}

// Flash attention. 512 thr = 8 waves over a 128-q-row tile; wave owns 16 rows.
// Round-6: Pb is WAVE-PRIVATE (each wave writes+reads only its own 16 rows),
// so PV is split into two k-halves sharing a [128][72] buffer: LDS drops
// 66KB -> 50KB -> 3 blocks/CU (24 waves, 6/SIMD; VGPR=64 permits 8).
// KVBLK=128, 4 barriers/tile. KVb holds K then V^T (pre-transposed Vt);
// V^T staged async right after QK^T -> latency hides under softmax.
__global__ __launch_bounds__(512, 4) void attn(
    const u16* __restrict__ Q,   // [MROWS][HIDDEN] bf16
    const u16* __restrict__ Kv,  // [KVLEN][HIDDEN] bf16
    const u16* __restrict__ Vt,  // [HEADS*HDIM][KVLEN] bf16 (per-head V^T)
    u16* __restrict__ O) {       // [MROWS][HIDDEN] bf16
  __shared__ __align__(16) u16 KVb[16 * 1024];   // K: [d/8 16][kv 128][8d]; V: [kv/8 16][d 128][8kv]
  __shared__ __align__(16) __bf16 Pb[128 * 72];  // [q 128][64 + 8 pad], holds ONE k-half
  const int tid = threadIdx.x;
  const int wid = tid >> 6, lane = tid & 63;    // wid 0..7
  const int quad = lane >> 4, l15 = lane & 15;
  // XCD swizzle: 128 consecutive swizzled ids = 2 heads -> K+V slice 4MB = one L2
  const int lin = blockIdx.x + (blockIdx.y << 3) + (blockIdx.z << 7);
  const int swz = ((lin & 7) << 7) + (lin >> 3);
  const int h = swz >> 6, b = (swz >> 3) & 7, qt = swz & 7;
  const int qrow0 = b * QLEN + qt * 128;
  const int hcol = h * HDIM;
  const float cexp = 0.08838834764831845f * 1.4426950408889634f;  // SCALE*log2(e)

  bf16x8 qf[4];
#pragma unroll
  for (int ks = 0; ks < 4; ks++) {
    int row = qrow0 + wid * 16 + l15;
    qf[ks] = *(const bf16x8*)(Q + (size_t)row * HIDDEN + hcol + ks * 32 + quad * 8);
  }

  f32x4 o[8];
#pragma unroll
  for (int dt = 0; dt < 8; dt++) o[dt] = (f32x4){0.f, 0.f, 0.f, 0.f};
  float mrun[4], lrun[4];
#pragma unroll
  for (int r = 0; r < 4; r++) { mrun[r] = -INFINITY; lrun[r] = 0.f; }

  for (int kv0 = 0; kv0 < KVLEN; kv0 += 128) {
    __syncthreads();  // (a) prev PV reads of KVb done
#pragma unroll
    for (int i = 0; i < 4; i++) {
      int seg = wid + 8 * i;        // 0..31
      int ch = seg >> 1, sh = seg & 1;
      int kvr = kv0 + sh * 64 + lane;
      const u16* g = Kv + (size_t)kvr * HIDDEN + hcol + ch * 8;
      async_ld16(g, KVb + (ch * 128 + sh * 64) * 8);  // wave-uniform dest
    }
    __syncthreads();  // (b) K ready

    f32x4 sc[8];
#pragma unroll
    for (int nt = 0; nt < 8; nt++) sc[nt] = (f32x4){0.f, 0.f, 0.f, 0.f};
#pragma unroll
    for (int ks = 0; ks < 4; ks++) {
#pragma unroll
      for (int hf = 0; hf < 2; hf++) {   // 4-reg batches: limit transient VGPRs
        bf16x8 kf[4];
#pragma unroll
        for (int j = 0; j < 4; j++)
          kf[j] = *(const bf16x8*)(KVb + ((ks * 4 + quad) * 128 + (hf * 4 + j) * 16 + l15) * 8);
#pragma unroll
        for (int j = 0; j < 4; j++)
          sc[hf * 4 + j] = __builtin_amdgcn_mfma_f32_16x16x32_bf16(qf[ks], kf[j], sc[hf * 4 + j], 0, 0, 0);
      }
    }
    __syncthreads();  // (c) K reads done -> KVb reusable for V

    // Issue V^T stage now (async into KVb); drains at (d). Latency hides
    // under softmax below, which touches only registers/shuffles/Pb.
#pragma unroll
    for (int i = 0; i < 4; i++) {
      int seg = wid + 8 * i;             // 0..31
      int ch = seg >> 1, dh = seg & 1;   // kv-octet, d-half
      int d = dh * 64 + lane;
      const u16* g = Vt + ((size_t)hcol + d) * KVLEN + kv0 + ch * 8;
      async_ld16(g, KVb + (ch * 128 + dh * 64) * 8);  // wave-uniform dest
    }

    // --- online softmax with defer-max (T13, THR=8 in raw-score units) ---
    float mx[4];
#pragma unroll
    for (int r = 0; r < 4; r++) {
      float m = sc[0][r];
#pragma unroll
      for (int nt = 1; nt < 8; nt++) m = fmaxf(m, sc[nt][r]);
#pragma unroll
      for (int off = 1; off < 16; off <<= 1) m = fmaxf(m, __shfl_xor(m, off, 64));
      mx[r] = m;
    }
    float gmax = fmaxf(fmaxf(mx[0] - mrun[0], mx[1] - mrun[1]),
                       fmaxf(mx[2] - mrun[2], mx[3] - mrun[3]));
    if (__any(gmax > 8.f)) {   // wave-uniform branch
#pragma unroll
      for (int r = 0; r < 4; r++) {
        float mn = fmaxf(mrun[r], mx[r]);
        float al = __builtin_amdgcn_exp2f((mrun[r] - mn) * cexp);
        mrun[r] = mn;
        lrun[r] *= al;
#pragma unroll
        for (int dt = 0; dt < 8; dt++) o[dt][r] *= al;
      }
    }
#pragma unroll
    for (int r = 0; r < 4; r++) {
      float mc = mrun[r] * cexp;
      float ps = 0.f;
#pragma unroll
      for (int nt = 0; nt < 8; nt++) {
        float p = __builtin_amdgcn_exp2f(sc[nt][r] * cexp - mc);
        sc[nt][r] = p;
        ps += p;
      }
#pragma unroll
      for (int off = 1; off < 16; off <<= 1) ps += __shfl_xor(ps, off, 64);
      lrun[r] += ps;
    }

    // write P k-half 0 (cols 0..63) -- Pb rows are wave-private, no barrier
#pragma unroll
    for (int nt = 0; nt < 4; nt++)
#pragma unroll
      for (int r = 0; r < 4; r++) {
        int prow = wid * 16 + quad * 4 + r;
        Pb[prow * 72 + nt * 16 + l15] = (__bf16)sc[nt][r];
      }
    __syncthreads();  // (d) drains V loads (vmcnt); half0 writes also visible

    // PV k-half 0 (ks = 0,1)
#pragma unroll
    for (int ks2 = 0; ks2 < 2; ks2++) {
      bf16x8 pf = *(const bf16x8*)(Pb + (wid * 16 + l15) * 72 + ks2 * 32 + quad * 8);
#pragma unroll
      for (int hf = 0; hf < 2; hf++) {
        bf16x8 vf[4];
#pragma unroll
        for (int j = 0; j < 4; j++)
          vf[j] = *(const bf16x8*)(KVb + ((ks2 * 4 + quad) * 128 + (hf * 4 + j) * 16 + l15) * 8);
#pragma unroll
        for (int j = 0; j < 4; j++)
          o[hf * 4 + j] = __builtin_amdgcn_mfma_f32_16x16x32_bf16(pf, vf[j], o[hf * 4 + j], 0, 0, 0);
      }
    }

    // write P k-half 1 (cols 64..127 -> same Pb slots). Per-wave in-order DS
    // + may-alias ordering guarantee the half0 pf reads above complete first.
#pragma unroll
    for (int nt = 0; nt < 4; nt++)
#pragma unroll
      for (int r = 0; r < 4; r++) {
        int prow = wid * 16 + quad * 4 + r;
        Pb[prow * 72 + nt * 16 + l15] = (__bf16)sc[4 + nt][r];
      }

    // PV k-half 1 (ks = 2,3)
#pragma unroll
    for (int ks2 = 0; ks2 < 2; ks2++) {
      bf16x8 pf = *(const bf16x8*)(Pb + (wid * 16 + l15) * 72 + ks2 * 32 + quad * 8);
#pragma unroll
      for (int hf = 0; hf < 2; hf++) {
        bf16x8 vf[4];
#pragma unroll
        for (int j = 0; j < 4; j++)
          vf[j] = *(const bf16x8*)(KVb + (((2 + ks2) * 4 + quad) * 128 + (hf * 4 + j) * 16 + l15) * 8);
#pragma unroll
        for (int j = 0; j < 4; j++)
          o[hf * 4 + j] = __builtin_amdgcn_mfma_f32_16x16x32_bf16(pf, vf[j], o[hf * 4 + j], 0, 0, 0);
      }
    }
  }

#pragma unroll
  for (int r = 0; r < 4; r++) {
    float inv = 1.0f / lrun[r];
    int row = qrow0 + wid * 16 + quad * 4 + r;
#pragma unroll
    for (int dt = 0; dt < 8; dt++) {
      int col = hcol + dt * 16 + l15;
      ((__bf16*)O)[(size_t)row * HIDDEN + col] = (__bf16)(o[dt][r] * inv);
    }
  }
}

extern "C" void kernel_launch(void* const* d_in, const int* in_sizes, int n_in,
                              void* d_out, int out_size, void* d_ws, size_t ws_size,
                              hipStream_t stream) {
  const float* query = (const float*)d_in[0];
  const float* kv_k  = (const float*)d_in[1];
  const float* kv_v  = (const float*)d_in[2];
  const float* Wq    = (const float*)d_in[3];
  const float* Wo    = (const float*)d_in[4];
  float* out = (float*)d_out;

  const long NQ = (long)MROWS * HIDDEN;   // 16.78M
  const long NK = (long)KVLEN * HIDDEN;   // 8.39M
  const long NW = (long)HIDDEN * HIDDEN;  // 4.19M

  dim3 blk(256);

  // ws (u16): [convQ NQ][convK NK][Vt NK][convWq NW][convWo NW][Qws NQ]; Ows aliases convQ.
  u16* convQ  = (u16*)d_ws;
  u16* convK  = convQ + NQ;
  u16* Vtb    = convK + NK;
  u16* convWq = Vtb + NK;
  u16* convWo = convWq + NW;
  u16* Qws    = convWo + NW;
  u16* Ows    = convQ;  // convQ dead after gemm1

  convert_bf16<<<dim3((NQ / 8 + 255) / 256), blk, 0, stream>>>(query, convQ,  NQ);
  convert_bf16<<<dim3((NK / 8 + 255) / 256), blk, 0, stream>>>(kv_k,  convK,  NK);
  transpose_v<<<dim3(KVLEN / 128, HEADS), blk, 0, stream>>>(kv_v, Vtb);
  convert_bf16<<<dim3((NW / 8 + 255) / 256), blk, 0, stream>>>(Wq,    convWq, NW);
  convert_bf16<<<dim3((NW / 8 + 255) / 256), blk, 0, stream>>>(Wo,    convWo, NW);

  gemm_bt<<<dim3(HIDDEN / 128, MROWS / 128), blk, 0, stream>>>(convQ, convWq, Qws, MROWS, HIDDEN, HIDDEN, 0);
  attn<<<dim3(QLEN / 128, HEADS, BQ), dim3(512), 0, stream>>>(Qws, convK, Vtb, Ows);
  gemm_bt<<<dim3(HIDDEN / 128, MROWS / 128), blk, 0, stream>>>(Ows, convWo, out, MROWS, HIDDEN, HIDDEN, 1);
}